// Round 1
// baseline (76.481 us; speedup 1.0000x reference)
//
#include <hip/hip_runtime.h>

// Depthwise 3x3 ones-kernel conv (overlap-sum), zero-padded, stride 1.
// x: (64, 512, 40, 40) fp32 -> out: same shape.
// One block per 40x40 plane. Separable: horizontal 3-sum then vertical 3-sum.

#define PLANE_ELEMS 1600   // 40*40
#define PLANE_VEC4  400    // 1600/4
#define W 40

__global__ __launch_bounds__(256) void overlap_sum_3x3(
    const float* __restrict__ in, float* __restrict__ out)
{
    __shared__ float s_a[PLANE_ELEMS];  // input, later reused for vertical sum
    __shared__ float s_h[PLANE_ELEMS];  // horizontal 3-sum

    const int t = threadIdx.x;
    const size_t plane_off = (size_t)blockIdx.x * PLANE_ELEMS;

    // ---- Stage plane into LDS with float4 loads (400 vec4 / 256 threads) ----
    const float4* src4 = reinterpret_cast<const float4*>(in + plane_off);
    float4* s_a4 = reinterpret_cast<float4*>(s_a);
    s_a4[t] = src4[t];                       // t in [0,256)
    if (t < PLANE_VEC4 - 256) s_a4[t + 256] = src4[t + 256];  // t in [0,144)
    __syncthreads();

    // ---- Horizontal 3-sum: s_h[y][x] = a[y][x-1] + a[y][x] + a[y][x+1] ----
    #pragma unroll
    for (int i = t; i < PLANE_ELEMS; i += 256) {
        const int x = i % W;
        const float v = s_a[i];
        const float l = (x > 0)     ? s_a[i - 1] : 0.0f;
        const float r = (x < W - 1) ? s_a[i + 1] : 0.0f;
        s_h[i] = l + v + r;
    }
    __syncthreads();

    // ---- Vertical 3-sum into s_a (input no longer needed) ----
    #pragma unroll
    for (int i = t; i < PLANE_ELEMS; i += 256) {
        const float v = s_h[i];
        const float u = (i >= W)                 ? s_h[i - W] : 0.0f;
        const float d = (i < PLANE_ELEMS - W)    ? s_h[i + W] : 0.0f;
        s_a[i] = u + v + d;
    }
    __syncthreads();

    // ---- Store with float4 ----
    float4* dst4 = reinterpret_cast<float4*>(out + plane_off);
    dst4[t] = s_a4[t];
    if (t < PLANE_VEC4 - 256) dst4[t + 256] = s_a4[t + 256];
}

extern "C" void kernel_launch(void* const* d_in, const int* in_sizes, int n_in,
                              void* d_out, int out_size, void* d_ws, size_t ws_size,
                              hipStream_t stream) {
    const float* x = (const float*)d_in[0];
    float* out = (float*)d_out;
    // 64 * 512 planes of 40x40
    const int n_planes = in_sizes[0] / PLANE_ELEMS;   // 32768
    overlap_sum_3x3<<<n_planes, 256, 0, stream>>>(x, out);
}